// Round 3
// baseline (307.249 us; speedup 1.0000x reference)
//
#include <hip/hip_runtime.h>
#include <hip/hip_bf16.h>

// B=2048, T=32, V=1024, D=256
// idx[b][t] = argmin_v (c2[t][v] - 2*x[b][t].c[t][v]);  embed = gathered codebook rows.
// R2: occupancy attack. Counters showed everything idle (Mfma 7%, VALU 13%,
// HBM 16%, occupancy 21%) -> latency-bound with 2 waves/SIMD. BT 128->64 cuts
// A_lds to 32KB => ~38KB LDS => 4 blocks/CU = 16 waves/CU. Ballot-based
// candidate append (1 atomic/wave-pred). B stays global->reg (L2-resident),
// 2-buffer prefetch over fully-unrolled (vt,kc) stream.

#define B_ 2048
#define T_ 32
#define V_ 1024
#define D_ 256
#define BT 64
#define VT 128
#define NVT 8
#define CAND_MAX 1024
#define MARGIN 8.0f

typedef __attribute__((ext_vector_type(8))) short short8;   // 8 bf16 = 4 VGPR
typedef __attribute__((ext_vector_type(4))) float f32x4;

__device__ __forceinline__ unsigned short f2bf(float f) {
    unsigned u = __builtin_bit_cast(unsigned, f);
    unsigned r = u + 0x7FFFu + ((u >> 16) & 1u);
    return (unsigned short)(r >> 16);
}

__device__ __forceinline__ short8 pack8(float4 a, float4 b) {
    short8 r;
    r[0] = (short)f2bf(a.x); r[1] = (short)f2bf(a.y);
    r[2] = (short)f2bf(a.z); r[3] = (short)f2bf(a.w);
    r[4] = (short)f2bf(b.x); r[5] = (short)f2bf(b.y);
    r[6] = (short)f2bf(b.z); r[7] = (short)f2bf(b.w);
    return r;
}

// ---- prep (fused): c2 exact fp32 + codebook -> plain row-major bf16
__global__ void prep_kernel(const float* __restrict__ cb, float* __restrict__ c2,
                            unsigned short* __restrict__ cbb) {
    const int wave = threadIdx.x >> 6, lane = threadIdx.x & 63;
    const int row = blockIdx.x * 4 + wave;                 // t*V + v
    const float4 v4 = *(const float4*)(cb + (size_t)row * D_ + lane * 4);
    float s = v4.x * v4.x + v4.y * v4.y + v4.z * v4.z + v4.w * v4.w;
    #pragma unroll
    for (int off = 32; off; off >>= 1) s += __shfl_down(s, off, 64);
    if (lane == 0) c2[row] = s;

    ushort4 b4;
    b4.x = f2bf(v4.x); b4.y = f2bf(v4.y); b4.z = f2bf(v4.z); b4.w = f2bf(v4.w);
    *(ushort4*)(cbb + (size_t)row * D_ + lane * 4) = b4;
}

// ---- fallback prep when ws too small: c2 only
__global__ void c2_kernel(const float* __restrict__ cb, float* __restrict__ c2) {
    const int row = blockIdx.x * 4 + (threadIdx.x >> 6);
    const int lane = threadIdx.x & 63;
    const float4 v = ((const float4*)(cb + (size_t)row * D_))[lane];
    float s = v.x * v.x + v.y * v.y + v.z * v.z + v.w * v.w;
    #pragma unroll
    for (int off = 32; off; off >>= 1) s += __shfl_down(s, off, 64);
    if (lane == 0) c2[row] = s;
}

// ---------------- main ----------------
__global__ __launch_bounds__(256, 4)
void vq_kernel(const float* __restrict__ x, const float* __restrict__ cb,
               const float* __restrict__ c2, const unsigned short* __restrict__ cbb,
               float* __restrict__ out, int use_bf) {
    const int t  = blockIdx.x;
    const int b0 = blockIdx.y * BT;

    // LDS = 32768 + 512 + 512 + 4096 + 4 ~= 38 KB -> 4 blocks/CU
    __shared__ short8 A_lds[BT * 32];         // 64 rows x 32 granules, XOR(r&15)
    __shared__ float  minPart[BT * 2];        // cumulative row-min per wn half
    __shared__ unsigned long long result[BT];
    __shared__ unsigned s_cand[CAND_MAX];
    __shared__ unsigned s_cnt;

    const int tid = threadIdx.x;
    const int wave = tid >> 6, lane = tid & 63;
    const int wm = wave & 1, wn = wave >> 1;
    const int q = lane >> 4, ln = lane & 15;

    if (tid < BT) result[tid] = ~0ULL;
    if (tid < BT * 2) minPart[tid] = 3.4e38f;
    if (tid == 0) s_cnt = 0;

    // stage A once (fp32 -> bf16, XOR swizzle): 64 rows x 32 granules
    #pragma unroll
    for (int i = 0; i < 8; ++i) {
        int gid = i * 256 + tid, r = gid >> 5, g = gid & 31;
        const float4* src = (const float4*)(x + (((size_t)(b0 + r)) * T_ + t) * D_ + g * 8);
        A_lds[r * 32 + (g ^ (r & 15))] = pack8(src[0], src[1]);
    }

    // B direct-load lane bases: lane (q,ln) of wave-col wn owns row wn*64+nt*16+ln,
    // k-granule q of the current kc chunk (16B; 4 q-lanes share one 64B line).
    const unsigned short* bb = cbb + ((size_t)t * V_ + wn * 64 + ln) * D_ + q * 8;
    const float*          fb = cb  + ((size_t)t * V_ + wn * 64 + ln) * D_ + q * 8;

    auto loadB = [&](int vt, int kc, short8 (&dst)[4]) {
        #pragma unroll
        for (int nt = 0; nt < 4; ++nt) {
            const int off = (vt * VT + nt * 16) * D_ + kc * 32;
            if (use_bf) {
                dst[nt] = *(const short8*)(bb + off);
            } else {
                const float4* s = (const float4*)(fb + off);
                dst[nt] = pack8(s[0], s[1]);
            }
        }
    };

    short8 bufs[2][4];
    loadB(0, 0, bufs[0]);
    __syncthreads();                 // A_lds writes + inits visible

    const int abase = (wm * 32 + ln) * 32;

    #pragma unroll
    for (int vt = 0; vt < NVT; ++vt) {
        f32x4 acc[2][4];
        #pragma unroll
        for (int mt = 0; mt < 2; ++mt)
            #pragma unroll
            for (int nt = 0; nt < 4; ++nt) acc[mt][nt] = (f32x4){0.f, 0.f, 0.f, 0.f};

        #pragma unroll
        for (int kc = 0; kc < 8; ++kc) {
            // prefetch next step (crosses vt boundary; lands during epilogue)
            if (!(vt == NVT - 1 && kc == 7)) {
                const int s1 = vt * 8 + kc + 1;
                loadB(s1 >> 3, s1 & 7, bufs[(kc + 1) & 1]);
            }
            short8 af[2];
            af[0] = A_lds[abase + ((kc * 4 + q) ^ ln)];
            af[1] = A_lds[abase + 512 + ((kc * 4 + q) ^ ln)];
            #pragma unroll
            for (int mt = 0; mt < 2; ++mt)
                #pragma unroll
                for (int nt = 0; nt < 4; ++nt)
                    acc[mt][nt] = __builtin_amdgcn_mfma_f32_16x16x32_bf16(
                        af[mt], bufs[kc & 1][nt], acc[mt][nt], 0, 0, 0);
        }

        // ---- epilogue: update shared running row-min, then collect candidates
        const float* c2p = c2 + t * V_ + vt * VT + wn * 64 + ln;
        float cc[4];
        #pragma unroll
        for (int nt = 0; nt < 4; ++nt) cc[nt] = c2p[nt * 16];

        #pragma unroll
        for (int mt = 0; mt < 2; ++mt)
            #pragma unroll
            for (int i = 0; i < 4; ++i) {
                float mn = 3.4e38f;
                #pragma unroll
                for (int nt = 0; nt < 4; ++nt)
                    mn = fminf(mn, fmaf(-2.0f, acc[mt][nt][i], cc[nt]));
                mn = fminf(mn, __shfl_xor(mn, 1, 64));
                mn = fminf(mn, __shfl_xor(mn, 2, 64));
                mn = fminf(mn, __shfl_xor(mn, 4, 64));
                mn = fminf(mn, __shfl_xor(mn, 8, 64));
                if (ln == 0) {
                    int r = wm * 32 + mt * 16 + q * 4 + i;
                    minPart[r * 2 + wn] = fminf(minPart[r * 2 + wn], mn);
                }
            }
        __syncthreads();   // this vt's min visible to both wn halves

        #pragma unroll
        for (int mt = 0; mt < 2; ++mt)
            #pragma unroll
            for (int i = 0; i < 4; ++i) {
                const int r = wm * 32 + mt * 16 + q * 4 + i;
                float2 mp = *(const float2*)&minPart[r * 2];
                float thr = fminf(mp.x, mp.y) + MARGIN;
                #pragma unroll
                for (int nt = 0; nt < 4; ++nt) {
                    float s = fmaf(-2.0f, acc[mt][nt][i], cc[nt]);
                    const bool pred = (s < thr);
                    unsigned long long m = __ballot(pred);
                    if (m) {
                        const int first = __ffsll((unsigned long long)m) - 1;
                        unsigned base = 0;
                        if (lane == first) base = atomicAdd(&s_cnt, (unsigned)__popcll(m));
                        base = __shfl(base, first, 64);
                        if (pred) {
                            unsigned pos = base + (unsigned)__popcll(m & ((1ull << lane) - 1ull));
                            if (pos < CAND_MAX) {
                                int v = vt * VT + wn * 64 + nt * 16 + ln;
                                s_cand[pos] = (unsigned)((r << 10) | v);
                            }
                        }
                    }
                }
            }
        // no barrier: minPart cells are single-writer, monotone-decreasing, so a
        // faster wave's next-vt update only tightens thresholds (still a superset).
    }

    // ---- exact fp32 rescore of candidates (16-lane groups)
    __syncthreads();
    const unsigned ncand = min(s_cnt, (unsigned)CAND_MAX);
    const int grp = tid >> 4, l16 = tid & 15;
    for (unsigned ci = grp; ci < ncand; ci += 16) {
        const unsigned e = s_cand[ci];
        const int row = e >> 10, v = e & 1023;
        const float* xr = x + (((size_t)(b0 + row)) * T_ + t) * D_ + l16 * 16;
        const float* cr = cb + ((size_t)t * V_ + v) * D_ + l16 * 16;
        float dot = 0.f;
        #pragma unroll
        for (int j = 0; j < 4; ++j) {
            float4 a = *(const float4*)(xr + j * 4);
            float4 b = *(const float4*)(cr + j * 4);
            dot = fmaf(a.x, b.x, dot); dot = fmaf(a.y, b.y, dot);
            dot = fmaf(a.z, b.z, dot); dot = fmaf(a.w, b.w, dot);
        }
        dot += __shfl_xor(dot, 1, 64);
        dot += __shfl_xor(dot, 2, 64);
        dot += __shfl_xor(dot, 4, 64);
        dot += __shfl_xor(dot, 8, 64);
        if (l16 == 0) {
            float sc = fmaf(-2.0f, dot, c2[t * V_ + v]);
            unsigned u = __builtin_bit_cast(unsigned, sc);
            u = (u & 0x80000000u) ? ~u : (u | 0x80000000u);   // sortable fp32
            atomicMin(&result[row], ((unsigned long long)u << 32) | (unsigned)v);
        }
    }
    __syncthreads();

    if (tid < BT)
        out[(size_t)B_ * T_ * D_ + (size_t)(b0 + tid) * T_ + t] =
            (float)(int)(result[tid] & 1023u);

    // ---- fused gather: 16 rows per wave, one float4 per lane per row
    #pragma unroll
    for (int i = 0; i < 16; ++i) {
        const int row = wave * 16 + i;
        const int idx = (int)(result[row] & 1023u);
        const float4 src = *(const float4*)(cb + ((size_t)t * V_ + idx) * D_ + lane * 4);
        *(float4*)(out + (((size_t)(b0 + row)) * T_ + t) * D_ + lane * 4) = src;
    }
}

extern "C" void kernel_launch(void* const* d_in, const int* in_sizes, int n_in,
                              void* d_out, int out_size, void* d_ws, size_t ws_size,
                              hipStream_t stream) {
    const float* x  = (const float*)d_in[0];   // (B,T,D)
    const float* cb = (const float*)d_in[1];   // (T,V,D)
    float* out = (float*)d_out;                // embed fp32 ++ idx (as float)
    float* c2  = (float*)d_ws;                 // 32768 floats = 128 KB
    unsigned short* cbb = (unsigned short*)((char*)d_ws + 131072);  // 16 MB bf16 codebook
    const size_t NEED = 131072 + (size_t)T_ * V_ * D_ * 2;
    const int use_bf = (ws_size >= NEED) ? 1 : 0;

    if (use_bf) prep_kernel<<<dim3(T_ * V_ / 4), 256, 0, stream>>>(cb, c2, cbb);
    else        c2_kernel<<<dim3(T_ * V_ / 4), 256, 0, stream>>>(cb, c2);
    vq_kernel<<<dim3(T_, B_ / BT), 256, 0, stream>>>(x, cb, c2, cbb, out, use_bf);
}

// Round 5
// 281.384 us; speedup vs baseline: 1.0919x; 1.0919x over previous
//
#include <hip/hip_runtime.h>
#include <hip/hip_bf16.h>

// B=2048, T=32, V=1024, D=256
// idx[b][t] = argmin_v (c2[t][v] - 2*x[b][t].c[t][v]);  embed = gathered codebook rows.
// R3: line-request-traffic attack. R1/R2 showed throughput invariant under 2x
// occupancy with all pipes idle => saturated cache-line request path. Fixes:
// (1) disjoint per-wave V-slices (no duplicated B loads across wm pairs),
// (2) per-row candidate buckets + x-row-resident rescore (1 x-row load per row,
//     not per candidate), no atomicMin,
// (3) templated USE_BF, launch_bounds(256,3) to avoid the VGPR=64 spill corner.

#define B_ 2048
#define T_ 32
#define V_ 1024
#define D_ 256
#define BT 64
#define VTILE 256
#define NVT 4          // V_/VTILE
#define CAP 32
#define MARGIN 8.0f

typedef __attribute__((ext_vector_type(8))) short short8;   // 8 bf16 = 4 VGPR
typedef __attribute__((ext_vector_type(4))) float f32x4;

__device__ __forceinline__ unsigned short f2bf(float f) {
    unsigned u = __builtin_bit_cast(unsigned, f);
    unsigned r = u + 0x7FFFu + ((u >> 16) & 1u);
    return (unsigned short)(r >> 16);
}

__device__ __forceinline__ short8 pack8(float4 a, float4 b) {
    short8 r;
    r[0] = (short)f2bf(a.x); r[1] = (short)f2bf(a.y);
    r[2] = (short)f2bf(a.z); r[3] = (short)f2bf(a.w);
    r[4] = (short)f2bf(b.x); r[5] = (short)f2bf(b.y);
    r[6] = (short)f2bf(b.z); r[7] = (short)f2bf(b.w);
    return r;
}

// ---- prep (fused): c2 exact fp32 + codebook -> plain row-major bf16
__global__ void prep_kernel(const float* __restrict__ cb, float* __restrict__ c2,
                            unsigned short* __restrict__ cbb) {
    const int wave = threadIdx.x >> 6, lane = threadIdx.x & 63;
    const int row = blockIdx.x * 4 + wave;                 // t*V + v
    const float4 v4 = *(const float4*)(cb + (size_t)row * D_ + lane * 4);
    float s = v4.x * v4.x + v4.y * v4.y + v4.z * v4.z + v4.w * v4.w;
    #pragma unroll
    for (int off = 32; off; off >>= 1) s += __shfl_down(s, off, 64);
    if (lane == 0) c2[row] = s;

    ushort4 b4;
    b4.x = f2bf(v4.x); b4.y = f2bf(v4.y); b4.z = f2bf(v4.z); b4.w = f2bf(v4.w);
    *(ushort4*)(cbb + (size_t)row * D_ + lane * 4) = b4;
}

// ---- fallback prep when ws too small: c2 only
__global__ void c2_kernel(const float* __restrict__ cb, float* __restrict__ c2) {
    const int row = blockIdx.x * 4 + (threadIdx.x >> 6);
    const int lane = threadIdx.x & 63;
    const float4 v = ((const float4*)(cb + (size_t)row * D_))[lane];
    float s = v.x * v.x + v.y * v.y + v.z * v.z + v.w * v.w;
    #pragma unroll
    for (int off = 32; off; off >>= 1) s += __shfl_down(s, off, 64);
    if (lane == 0) c2[row] = s;
}

// ---------------- main ----------------
template<int USE_BF>
__global__ __launch_bounds__(256, 3)
void vq_kernel(const float* __restrict__ x, const float* __restrict__ cb,
               const float* __restrict__ c2, const unsigned short* __restrict__ cbb,
               float* __restrict__ out) {
    const int t  = blockIdx.x;
    const int b0 = blockIdx.y * BT;

    // LDS = 32768 + 1024 + 256 + 4096 + 128 ~= 37.4 KB -> 4 blocks/CU
    __shared__ short8 A_lds[BT * 32];          // 64 rows x 32 granules, XOR(r&15)
    __shared__ float  minPart4[BT][4];         // per-row per-wave running min
    __shared__ unsigned rowCnt[BT];
    __shared__ unsigned short rowCand[BT * CAP];
    __shared__ unsigned short rowIdx[BT];

    const int tid = threadIdx.x;
    const int w = tid >> 6, lane = tid & 63;
    const int q = lane >> 4, ln = lane & 15;

    if (tid < BT) rowCnt[tid] = 0;
    ((float*)minPart4)[tid] = 3.4e38f;         // 256 = BT*4 exactly

    // stage A once (fp32 -> bf16, XOR swizzle): 64 rows x 32 granules
    #pragma unroll
    for (int i = 0; i < 8; ++i) {
        int gid = i * 256 + tid, r = gid >> 5, g = gid & 31;
        const float4* src = (const float4*)(x + (((size_t)(b0 + r)) * T_ + t) * D_ + g * 8);
        A_lds[r * 32 + (g ^ (r & 15))] = pack8(src[0], src[1]);
    }

    // B lane base: wave w owns V rows w*64 + nt*16 + ln (disjoint across waves)
    const unsigned short* bb = cbb + ((size_t)t * V_ + w * 64 + ln) * D_ + q * 8;
    const float*          fb = cb  + ((size_t)t * V_ + w * 64 + ln) * D_ + q * 8;

    auto loadB = [&](int vt, int kc, short8 (&dst)[4]) {
        #pragma unroll
        for (int nt = 0; nt < 4; ++nt) {
            const int off = (vt * VTILE + nt * 16) * D_ + kc * 32;
            if constexpr (USE_BF) {
                dst[nt] = *(const short8*)(bb + off);
            } else {
                const float4* s = (const float4*)(fb + off);
                dst[nt] = pack8(s[0], s[1]);
            }
        }
    };

    short8 bufs0[4], bufs1[4];
    loadB(0, 0, bufs0);
    __syncthreads();                 // A_lds writes + inits visible

    for (int vt = 0; vt < NVT; ++vt) {
        f32x4 acc[4][4];
        #pragma unroll
        for (int mt = 0; mt < 4; ++mt)
            #pragma unroll
            for (int nt = 0; nt < 4; ++nt) acc[mt][nt] = (f32x4){0.f, 0.f, 0.f, 0.f};

        #pragma unroll
        for (int kc = 0; kc < 8; ++kc) {
            // prefetch next global step (crosses vt boundary; lands during epilogue)
            if (!(vt == NVT - 1 && kc == 7)) {
                if (kc & 1) loadB(vt + (kc == 7), (kc + 1) & 7, bufs0);
                else        loadB(vt,             kc + 1,       bufs1);
            }
            short8 af[4];
            #pragma unroll
            for (int mt = 0; mt < 4; ++mt)
                af[mt] = A_lds[(mt * 16 + ln) * 32 + ((kc * 4 + q) ^ ln)];
            #pragma unroll
            for (int mt = 0; mt < 4; ++mt)
                #pragma unroll
                for (int nt = 0; nt < 4; ++nt)
                    acc[mt][nt] = __builtin_amdgcn_mfma_f32_16x16x32_bf16(
                        af[mt], (kc & 1) ? bufs1[nt] : bufs0[nt], acc[mt][nt], 0, 0, 0);
        }

        // ---- epilogue: per-wave row-min slots, then bucketed candidate collect
        const float* c2p = c2 + t * V_ + vt * VTILE + w * 64 + ln;
        float cc[4];
        #pragma unroll
        for (int nt = 0; nt < 4; ++nt) cc[nt] = c2p[nt * 16];

        #pragma unroll
        for (int mt = 0; mt < 4; ++mt)
            #pragma unroll
            for (int i = 0; i < 4; ++i) {
                float mn = 3.4e38f;
                #pragma unroll
                for (int nt = 0; nt < 4; ++nt)
                    mn = fminf(mn, fmaf(-2.0f, acc[mt][nt][i], cc[nt]));
                mn = fminf(mn, __shfl_xor(mn, 1, 64));
                mn = fminf(mn, __shfl_xor(mn, 2, 64));
                mn = fminf(mn, __shfl_xor(mn, 4, 64));
                mn = fminf(mn, __shfl_xor(mn, 8, 64));
                if (ln == 0) {
                    const int r = mt * 16 + q * 4 + i;
                    minPart4[r][w] = fminf(minPart4[r][w], mn);
                }
            }
        __syncthreads();   // this vt's 4-wave mins visible

        #pragma unroll
        for (int mt = 0; mt < 4; ++mt)
            #pragma unroll
            for (int i = 0; i < 4; ++i) {
                const int r = mt * 16 + q * 4 + i;
                const float4 mp = *(const float4*)minPart4[r];
                const float thr = fminf(fminf(mp.x, mp.y), fminf(mp.z, mp.w)) + MARGIN;
                #pragma unroll
                for (int nt = 0; nt < 4; ++nt) {
                    float s = fmaf(-2.0f, acc[mt][nt][i], cc[nt]);
                    if (s < thr) {
                        unsigned pos = atomicAdd(&rowCnt[r], 1u);
                        if (pos < CAP)
                            rowCand[r * CAP + pos] =
                                (unsigned short)(vt * VTILE + w * 64 + nt * 16 + ln);
                    }
                }
            }
        // no barrier: minPart4 cells are single-writer and monotone-decreasing,
        // so a faster wave's next-vt update only tightens thresholds (superset kept).
    }

    // ---- exact fp32 rescore: one 16-lane group per row, x-row held in regs
    __syncthreads();
    const int grp = tid >> 4, l16 = tid & 15;
    #pragma unroll
    for (int j = 0; j < 4; ++j) {
        const int r = grp * 4 + j;
        const float* xp = x + (((size_t)(b0 + r)) * T_ + t) * D_ + l16 * 16;
        float4 xr[4];
        #pragma unroll
        for (int k = 0; k < 4; ++k) xr[k] = ((const float4*)xp)[k];

        const unsigned cnt = rowCnt[r];
        unsigned long long best = ~0ULL;
        auto score_v = [&](int v) {
            const float* cr = cb + ((size_t)t * V_ + v) * D_ + l16 * 16;
            float dot = 0.f;
            #pragma unroll
            for (int k = 0; k < 4; ++k) {
                float4 b = ((const float4*)cr)[k];
                dot = fmaf(xr[k].x, b.x, dot); dot = fmaf(xr[k].y, b.y, dot);
                dot = fmaf(xr[k].z, b.z, dot); dot = fmaf(xr[k].w, b.w, dot);
            }
            dot += __shfl_xor(dot, 1, 64);
            dot += __shfl_xor(dot, 2, 64);
            dot += __shfl_xor(dot, 4, 64);
            dot += __shfl_xor(dot, 8, 64);
            float sc = fmaf(-2.0f, dot, c2[t * V_ + v]);
            unsigned u = __builtin_bit_cast(unsigned, sc);
            u = (u & 0x80000000u) ? ~u : (u | 0x80000000u);   // sortable fp32
            unsigned long long e = ((unsigned long long)u << 32) | (unsigned)v;
            if (e < best) best = e;
        };
        if (cnt <= CAP) {
            for (unsigned c = 0; c < cnt; ++c) score_v((int)rowCand[r * CAP + c]);
        } else {
            for (int v = 0; v < V_; ++v) score_v(v);   // overflow fallback (rare)
        }
        if (l16 == 0) rowIdx[r] = (unsigned short)(best & 1023u);
    }
    __syncthreads();

    if (tid < BT)
        out[(size_t)B_ * T_ * D_ + (size_t)(b0 + tid) * T_ + t] = (float)rowIdx[tid];

    // ---- fused gather: 16 rows per wave, one float4 per lane per row
    #pragma unroll
    for (int i = 0; i < 16; ++i) {
        const int row = w * 16 + i;
        const int idx = (int)rowIdx[row];
        const float4 src = *(const float4*)(cb + ((size_t)t * V_ + idx) * D_ + lane * 4);
        *(float4*)(out + (((size_t)(b0 + row)) * T_ + t) * D_ + lane * 4) = src;
    }
}

extern "C" void kernel_launch(void* const* d_in, const int* in_sizes, int n_in,
                              void* d_out, int out_size, void* d_ws, size_t ws_size,
                              hipStream_t stream) {
    const float* x  = (const float*)d_in[0];   // (B,T,D)
    const float* cb = (const float*)d_in[1];   // (T,V,D)
    float* out = (float*)d_out;                // embed fp32 ++ idx (as float)
    float* c2  = (float*)d_ws;                 // 32768 floats = 128 KB
    unsigned short* cbb = (unsigned short*)((char*)d_ws + 131072);  // 16 MB bf16 codebook
    const size_t NEED = 131072 + (size_t)T_ * V_ * D_ * 2;
    const int use_bf = (ws_size >= NEED) ? 1 : 0;

    if (use_bf) {
        prep_kernel<<<dim3(T_ * V_ / 4), 256, 0, stream>>>(cb, c2, cbb);
        vq_kernel<1><<<dim3(T_, B_ / BT), 256, 0, stream>>>(x, cb, c2, cbb, out);
    } else {
        c2_kernel<<<dim3(T_ * V_ / 4), 256, 0, stream>>>(cb, c2);
        vq_kernel<0><<<dim3(T_, B_ / BT), 256, 0, stream>>>(x, cb, c2, cbb, out);
    }
}

// Round 6
// 273.149 us; speedup vs baseline: 1.1248x; 1.0301x over previous
//
#include <hip/hip_runtime.h>
#include <hip/hip_bf16.h>

// B=2048, T=32, V=1024, D=256
// idx[b][t] = argmin_v (c2[t][v] - 2*x[b][t].c[t][v]);  embed = gathered codebook rows.
// R5: PHASE-SPLIT for attribution. Three structures (R1/R2/R3) all land ~185-207us
// with every pipe <15% busy; whole-kernel counters can't attribute the time.
// Split: main = MFMA sweep + threshold candidate collect (cand lists stashed in
// each row's embed slot of out, overwritten later); finish = exact fp32 rescore +
// idx + gather, separate dispatch (per-phase dur_us in rocprof). Prep gets 4
// rows/wave ILP (was 1 row/wave = serial 6-shuffle latency chain).

#define B_ 2048
#define T_ 32
#define V_ 1024
#define D_ 256
#define BT 64
#define VTILE 256
#define NVT 4          // V_/VTILE
#define CAP 32
#define MARGIN 8.0f

typedef __attribute__((ext_vector_type(8))) short short8;   // 8 bf16 = 4 VGPR
typedef __attribute__((ext_vector_type(4))) float f32x4;

__device__ __forceinline__ unsigned short f2bf(float f) {
    unsigned u = __builtin_bit_cast(unsigned, f);
    unsigned r = u + 0x7FFFu + ((u >> 16) & 1u);
    return (unsigned short)(r >> 16);
}

__device__ __forceinline__ short8 pack8(float4 a, float4 b) {
    short8 r;
    r[0] = (short)f2bf(a.x); r[1] = (short)f2bf(a.y);
    r[2] = (short)f2bf(a.z); r[3] = (short)f2bf(a.w);
    r[4] = (short)f2bf(b.x); r[5] = (short)f2bf(b.y);
    r[6] = (short)f2bf(b.z); r[7] = (short)f2bf(b.w);
    return r;
}

// ---- prep: c2 exact fp32 + codebook -> bf16; 4 rows/wave for ILP
__global__ void prep_kernel(const float* __restrict__ cb, float* __restrict__ c2,
                            unsigned short* __restrict__ cbb) {
    const int wave = threadIdx.x >> 6, lane = threadIdx.x & 63;
    const int row0 = blockIdx.x * 16 + wave * 4;
    float4 v4[4];
    float s[4];
    #pragma unroll
    for (int j = 0; j < 4; ++j) {
        v4[j] = *(const float4*)(cb + (size_t)(row0 + j) * D_ + lane * 4);
        s[j] = v4[j].x * v4[j].x + v4[j].y * v4[j].y
             + v4[j].z * v4[j].z + v4[j].w * v4[j].w;
    }
    #pragma unroll
    for (int off = 32; off; off >>= 1) {
        #pragma unroll
        for (int j = 0; j < 4; ++j) s[j] += __shfl_down(s[j], off, 64);
    }
    if (lane == 0) {
        #pragma unroll
        for (int j = 0; j < 4; ++j) c2[row0 + j] = s[j];
    }
    #pragma unroll
    for (int j = 0; j < 4; ++j) {
        ushort4 b4;
        b4.x = f2bf(v4[j].x); b4.y = f2bf(v4[j].y);
        b4.z = f2bf(v4[j].z); b4.w = f2bf(v4[j].w);
        *(ushort4*)(cbb + (size_t)(row0 + j) * D_ + lane * 4) = b4;
    }
}

// ---- fallback prep when ws too small: c2 only
__global__ void c2_kernel(const float* __restrict__ cb, float* __restrict__ c2) {
    const int row = blockIdx.x * 4 + (threadIdx.x >> 6);
    const int lane = threadIdx.x & 63;
    const float4 v = ((const float4*)(cb + (size_t)row * D_))[lane];
    float s = v.x * v.x + v.y * v.y + v.z * v.z + v.w * v.w;
    #pragma unroll
    for (int off = 32; off; off >>= 1) s += __shfl_down(s, off, 64);
    if (lane == 0) c2[row] = s;
}

// ---------------- main: MFMA sweep + candidate collect ----------------
template<int USE_BF>
__global__ __launch_bounds__(256, 3)
void main_kernel(const float* __restrict__ x, const float* __restrict__ cb,
                 const float* __restrict__ c2, const unsigned short* __restrict__ cbb,
                 float* __restrict__ out) {
    const int t  = blockIdx.x;
    const int b0 = blockIdx.y * BT;

    __shared__ short8 A_lds[BT * 32];          // 64 rows x 32 granules, XOR(r&15)
    __shared__ float  minPart4[BT][4];         // per-row per-wave running min
    __shared__ unsigned rowCnt[BT];
    __shared__ unsigned short rowCand[BT * CAP];

    const int tid = threadIdx.x;
    const int w = tid >> 6, lane = tid & 63;
    const int q = lane >> 4, ln = lane & 15;

    if (tid < BT) rowCnt[tid] = 0;
    ((float*)minPart4)[tid] = 3.4e38f;         // 256 = BT*4 exactly

    // stage A once (fp32 -> bf16, XOR swizzle): 64 rows x 32 granules
    #pragma unroll
    for (int i = 0; i < 8; ++i) {
        int gid = i * 256 + tid, r = gid >> 5, g = gid & 31;
        const float4* src = (const float4*)(x + (((size_t)(b0 + r)) * T_ + t) * D_ + g * 8);
        A_lds[r * 32 + (g ^ (r & 15))] = pack8(src[0], src[1]);
    }

    // B lane base: wave w owns V rows w*64 + nt*16 + ln (disjoint across waves)
    const unsigned short* bb = cbb + ((size_t)t * V_ + w * 64 + ln) * D_ + q * 8;
    const float*          fb = cb  + ((size_t)t * V_ + w * 64 + ln) * D_ + q * 8;

    auto loadB = [&](int vt, int kc, short8 (&dst)[4]) {
        #pragma unroll
        for (int nt = 0; nt < 4; ++nt) {
            const int off = (vt * VTILE + nt * 16) * D_ + kc * 32;
            if constexpr (USE_BF) {
                dst[nt] = *(const short8*)(bb + off);
            } else {
                const float4* s = (const float4*)(fb + off);
                dst[nt] = pack8(s[0], s[1]);
            }
        }
    };

    short8 bufs0[4], bufs1[4];
    loadB(0, 0, bufs0);
    __syncthreads();                 // A_lds writes + inits visible

    for (int vt = 0; vt < NVT; ++vt) {
        f32x4 acc[4][4];
        #pragma unroll
        for (int mt = 0; mt < 4; ++mt)
            #pragma unroll
            for (int nt = 0; nt < 4; ++nt) acc[mt][nt] = (f32x4){0.f, 0.f, 0.f, 0.f};

        #pragma unroll
        for (int kc = 0; kc < 8; ++kc) {
            if (!(vt == NVT - 1 && kc == 7)) {
                if (kc & 1) loadB(vt + (kc == 7), (kc + 1) & 7, bufs0);
                else        loadB(vt,             kc + 1,       bufs1);
            }
            short8 af[4];
            #pragma unroll
            for (int mt = 0; mt < 4; ++mt)
                af[mt] = A_lds[(mt * 16 + ln) * 32 + ((kc * 4 + q) ^ ln)];
            #pragma unroll
            for (int mt = 0; mt < 4; ++mt)
                #pragma unroll
                for (int nt = 0; nt < 4; ++nt)
                    acc[mt][nt] = __builtin_amdgcn_mfma_f32_16x16x32_bf16(
                        af[mt], (kc & 1) ? bufs1[nt] : bufs0[nt], acc[mt][nt], 0, 0, 0);
        }

        // ---- epilogue: per-wave row-min slots, then bucketed candidate collect
        const float* c2p = c2 + t * V_ + vt * VTILE + w * 64 + ln;
        float cc[4];
        #pragma unroll
        for (int nt = 0; nt < 4; ++nt) cc[nt] = c2p[nt * 16];

        #pragma unroll
        for (int mt = 0; mt < 4; ++mt)
            #pragma unroll
            for (int i = 0; i < 4; ++i) {
                float mn = 3.4e38f;
                #pragma unroll
                for (int nt = 0; nt < 4; ++nt)
                    mn = fminf(mn, fmaf(-2.0f, acc[mt][nt][i], cc[nt]));
                mn = fminf(mn, __shfl_xor(mn, 1, 64));
                mn = fminf(mn, __shfl_xor(mn, 2, 64));
                mn = fminf(mn, __shfl_xor(mn, 4, 64));
                mn = fminf(mn, __shfl_xor(mn, 8, 64));
                if (ln == 0) {
                    const int r = mt * 16 + q * 4 + i;
                    minPart4[r][w] = fminf(minPart4[r][w], mn);
                }
            }
        __syncthreads();   // this vt's 4-wave mins visible

        #pragma unroll
        for (int mt = 0; mt < 4; ++mt)
            #pragma unroll
            for (int i = 0; i < 4; ++i) {
                const int r = mt * 16 + q * 4 + i;
                const float4 mp = *(const float4*)minPart4[r];
                const float thr = fminf(fminf(mp.x, mp.y), fminf(mp.z, mp.w)) + MARGIN;
                #pragma unroll
                for (int nt = 0; nt < 4; ++nt) {
                    float s = fmaf(-2.0f, acc[mt][nt][i], cc[nt]);
                    if (s < thr) {
                        unsigned pos = atomicAdd(&rowCnt[r], 1u);
                        if (pos < CAP)
                            rowCand[r * CAP + pos] =
                                (unsigned short)(vt * VTILE + w * 64 + nt * 16 + ln);
                    }
                }
            }
        // no barrier: minPart4 cells are single-writer and monotone-decreasing,
        // so a faster wave's next-vt update only tightens thresholds (superset kept).
    }

    // ---- dump cnt + cand list into the row's own embed slot (finish overwrites)
    __syncthreads();
    if (tid < BT) {
        const int r = tid;
        unsigned* slot = (unsigned*)(out + (((size_t)(b0 + r)) * T_ + t) * D_);
        slot[0] = rowCnt[r];
        const unsigned short* rc = &rowCand[r * CAP];
        #pragma unroll
        for (int k = 0; k < CAP / 2; ++k)
            slot[1 + k] = (unsigned)rc[2 * k] | ((unsigned)rc[2 * k + 1] << 16);
    }
}

// ---------------- finish: exact fp32 rescore + idx + gather ----------------
__global__ __launch_bounds__(256, 8)
void finish_kernel(const float* __restrict__ x, const float* __restrict__ cb,
                   const float* __restrict__ c2, float* __restrict__ out) {
    const int t = blockIdx.x;
    const int b = blockIdx.y * 16 + (threadIdx.x >> 4);   // one row per 16-lane group
    const int l16 = threadIdx.x & 15;

    float* slot = out + ((size_t)b * T_ + t) * D_;
    const unsigned cnt = ((const unsigned*)slot)[0];

    const float* xp = x + ((size_t)b * T_ + t) * D_ + l16 * 16;
    float4 xr[4];
    #pragma unroll
    for (int k = 0; k < 4; ++k) xr[k] = ((const float4*)xp)[k];

    unsigned long long best = ~0ULL;
    auto score_v = [&](int v) {
        const float* cr = cb + ((size_t)t * V_ + v) * D_ + l16 * 16;
        float dot = 0.f;
        #pragma unroll
        for (int k = 0; k < 4; ++k) {
            float4 bv = ((const float4*)cr)[k];
            dot = fmaf(xr[k].x, bv.x, dot); dot = fmaf(xr[k].y, bv.y, dot);
            dot = fmaf(xr[k].z, bv.z, dot); dot = fmaf(xr[k].w, bv.w, dot);
        }
        dot += __shfl_xor(dot, 1, 64);
        dot += __shfl_xor(dot, 2, 64);
        dot += __shfl_xor(dot, 4, 64);
        dot += __shfl_xor(dot, 8, 64);
        float sc = fmaf(-2.0f, dot, c2[t * V_ + v]);
        unsigned u = __builtin_bit_cast(unsigned, sc);
        u = (u & 0x80000000u) ? ~u : (u | 0x80000000u);   // sortable fp32
        unsigned long long e = ((unsigned long long)u << 32) | (unsigned)v;
        if (e < best) best = e;
    };

    if (cnt <= CAP) {
        for (unsigned c = 0; c < cnt; ++c) {
            unsigned pr = ((const unsigned*)slot)[1 + (c >> 1)];
            score_v((int)((pr >> (16 * (c & 1))) & 0xffffu));
        }
    } else {
        for (int v = 0; v < V_; ++v) score_v(v);          // overflow fallback (rare)
    }

    // all 16 lanes hold identical best (uniform loop + full 16-lane reduce)
    const int idx = (int)(best & 1023u);
    if (l16 == 0) out[(size_t)B_ * T_ * D_ + (size_t)b * T_ + t] = (float)idx;

    // gather: overwrite slot with codebook row (reads of slot are done above)
    const float* cr = cb + ((size_t)t * V_ + idx) * D_;
    #pragma unroll
    for (int k = 0; k < 4; ++k)
        *(float4*)(slot + k * 64 + l16 * 4) = *(const float4*)(cr + k * 64 + l16 * 4);
}

extern "C" void kernel_launch(void* const* d_in, const int* in_sizes, int n_in,
                              void* d_out, int out_size, void* d_ws, size_t ws_size,
                              hipStream_t stream) {
    const float* x  = (const float*)d_in[0];   // (B,T,D)
    const float* cb = (const float*)d_in[1];   // (T,V,D)
    float* out = (float*)d_out;                // embed fp32 ++ idx (as float)
    float* c2  = (float*)d_ws;                 // 32768 floats = 128 KB
    unsigned short* cbb = (unsigned short*)((char*)d_ws + 131072);  // 16 MB bf16 codebook
    const size_t NEED = 131072 + (size_t)T_ * V_ * D_ * 2;
    const int use_bf = (ws_size >= NEED) ? 1 : 0;

    if (use_bf) {
        prep_kernel<<<dim3(T_ * V_ / 16), 256, 0, stream>>>(cb, c2, cbb);
        main_kernel<1><<<dim3(T_, B_ / BT), 256, 0, stream>>>(x, cb, c2, cbb, out);
    } else {
        c2_kernel<<<dim3(T_ * V_ / 4), 256, 0, stream>>>(cb, c2);
        main_kernel<0><<<dim3(T_, B_ / BT), 256, 0, stream>>>(x, cb, c2, cbb, out);
    }
    finish_kernel<<<dim3(T_, B_ / 16), 256, 0, stream>>>(x, cb, c2, out);
}